// Round 1
// 934.757 us; speedup vs baseline: 3.5722x; 3.5722x over previous
//
#include <hip/hip_runtime.h>
#include <math.h>

#define RBF 32
#define BLOCK 256
#define BT 512           // rbf rows staged per tile (contiguous in memory)
#define PAD 33           // padded LDS row stride: lane t reads bank (t+k)%32 -> conflict-free

// out[a,i] = sum_b cross(F1[a,b,:], L[b,:])_i
// F1[a,b,:] = unit(rij[a,b]) * radial[a,b]
// radial[a,b] = W2 . softplus(rbf[a,b,:] @ W1 + b1) + b2, masked if |rij|<1e-8
//
// Round-2 theory: FETCH was 8x ideal (each 128B rbf row-line re-fetched per
// float4 chunk after L2 eviction) and WRITE was 2GB of register spills.
// Now: cooperative contiguous staging of rbf[a, tile:tile+BT, :] into LDS
// (each HBM line fetched once, fully consumed), compute reads x from LDS
// (pad-33, conflict-free) and W1 from LDS (wave-uniform address = broadcast).
// 2 rows/thread keeps h-accumulators at 64 VGPRs; no global x regs -> no spill.
__global__ __launch_bounds__(BLOCK, 2)
void f1o1_kernel(const float* __restrict__ L,     // [N,3]
                 const float* __restrict__ rbf,   // [N,N,RBF]
                 const float* __restrict__ rij,   // [N,N,3]
                 const float* __restrict__ W1,    // [RBF,RBF]
                 const float* __restrict__ b1,    // [RBF]
                 const float* __restrict__ W2,    // [RBF]
                 const float* __restrict__ b2,    // [1]
                 float* __restrict__ out,         // [N,3]
                 int N)
{
    __shared__ float sW1[RBF * RBF];
    __shared__ float sb1[RBF];
    __shared__ float sW2[RBF];
    __shared__ float sx[BT * PAD];
    __shared__ float sred[4 * 3];

    const int t = threadIdx.x;
    const int a = blockIdx.x;

    for (int i = t; i < RBF * RBF; i += BLOCK) sW1[i] = W1[i];
    if (t < RBF) { sb1[t] = b1[t]; sW2[t] = W2[t]; }

    const float bias2 = b2[0];
    float acc0 = 0.f, acc1 = 0.f, acc2 = 0.f;
    const size_t abase = (size_t)a * (size_t)N;

    for (int tile = 0; tile < N; tile += BT) {
        const int rows = (N - tile < BT) ? (N - tile) : BT;
        const int nf4  = rows * (RBF / 4);

        __syncthreads();  // previous tile's readers done (also orders weight staging)

        // ---- cooperative stage: rbf[a, tile:tile+rows, :] -> sx ----
        // Block reads BT*RBF*4 = 64KB contiguous: perfectly coalesced, each
        // 128B line consumed exactly once at fetch time.
        const float4* gsrc = (const float4*)(rbf + (abase + (size_t)tile) * RBF);
        #pragma unroll
        for (int i = 0; i < (BT * RBF / 4) / BLOCK; ++i) {
            const int g = i * BLOCK + t;
            if (g < nf4) {
                float4 v = gsrc[g];
                const int r  = g >> 3;          // 8 float4 per row
                const int k4 = (g & 7) << 2;
                float* d = sx + r * PAD + k4;
                d[0] = v.x; d[1] = v.y; d[2] = v.z; d[3] = v.w;
            }
        }
        __syncthreads();

        // ---- compute: rows t and t+BLOCK of this tile ----
        float4 ha[RBF / 4], hb[RBF / 4];
        #pragma unroll
        for (int jq = 0; jq < RBF / 4; ++jq) {
            float4 bv = ((const float4*)sb1)[jq];
            ha[jq] = bv; hb[jq] = bv;
        }

        const float* xa = sx + t * PAD;
        const float* xb = sx + (t + BLOCK) * PAD;

        #pragma unroll 4
        for (int k = 0; k < RBF; ++k) {
            const float xsa = xa[k];            // bank (t+k)%32: conflict-free
            const float xsb = xb[k];            // (t+256+k)%32 == (t+k)%32
            const float4* w4 = (const float4*)(sW1 + k * RBF);  // uniform addr: broadcast
            #pragma unroll
            for (int jq = 0; jq < RBF / 4; ++jq) {
                const float4 w = w4[jq];
                ha[jq].x = fmaf(xsa, w.x, ha[jq].x);
                ha[jq].y = fmaf(xsa, w.y, ha[jq].y);
                ha[jq].z = fmaf(xsa, w.z, ha[jq].z);
                ha[jq].w = fmaf(xsa, w.w, ha[jq].w);
                hb[jq].x = fmaf(xsb, w.x, hb[jq].x);
                hb[jq].y = fmaf(xsb, w.y, hb[jq].y);
                hb[jq].z = fmaf(xsb, w.z, hb[jq].z);
                hb[jq].w = fmaf(xsb, w.w, hb[jq].w);
            }
        }

        // ---- softplus + Dense2 ----
        float ra = bias2, rb = bias2;
        #pragma unroll
        for (int jq = 0; jq < RBF / 4; ++jq) {
            const float4 w2v = ((const float4*)sW2)[jq];
            const float hav[4] = {ha[jq].x, ha[jq].y, ha[jq].z, ha[jq].w};
            const float hbv[4] = {hb[jq].x, hb[jq].y, hb[jq].z, hb[jq].w};
            const float w2s[4] = {w2v.x, w2v.y, w2v.z, w2v.w};
            #pragma unroll
            for (int c = 0; c < 4; ++c) {
                float va = hav[c];
                float spa = fmaxf(va, 0.f) + __logf(1.f + __expf(-fabsf(va)));
                ra = fmaf(spa, w2s[c], ra);
                float vb = hbv[c];
                float spb = fmaxf(vb, 0.f) + __logf(1.f + __expf(-fabsf(vb)));
                rb = fmaf(spb, w2s[c], rb);
            }
        }

        // ---- mask, unit vector, cross with L, accumulate ----
        #pragma unroll
        for (int u = 0; u < 2; ++u) {
            const int b = tile + t + u * BLOCK;
            if (b < N) {
                const float radial = (u == 0) ? ra : rb;
                const float* rr3 = rij + (abase + (size_t)b) * 3;  // 12B/lane, coalesced
                float r0 = rr3[0], r1 = rr3[1], r2 = rr3[2];
                float ss = r0 * r0 + r1 * r1 + r2 * r2;
                // dij < 1e-8  <=>  ss < 1e-16
                float scale = (ss < 1e-16f) ? 0.f : radial * rsqrtf(fmaxf(ss, 1e-8f));
                float f0 = r0 * scale, f1 = r1 * scale, f2 = r2 * scale;
                const float* lp = L + (size_t)b * 3;
                float l0 = lp[0], l1 = lp[1], l2 = lp[2];
                acc0 += f1 * l2 - f2 * l1;
                acc1 += f2 * l0 - f0 * l2;
                acc2 += f0 * l1 - f1 * l0;
            }
        }
    }

    // ---- wave reduction (64 lanes) + block reduction ----
    #pragma unroll
    for (int off = 32; off > 0; off >>= 1) {
        acc0 += __shfl_down(acc0, off, 64);
        acc1 += __shfl_down(acc1, off, 64);
        acc2 += __shfl_down(acc2, off, 64);
    }
    const int wv = t >> 6;
    if ((t & 63) == 0) {
        sred[wv * 3 + 0] = acc0;
        sred[wv * 3 + 1] = acc1;
        sred[wv * 3 + 2] = acc2;
    }
    __syncthreads();
    if (t < 3) {
        out[(size_t)a * 3 + t] = sred[t] + sred[3 + t] + sred[6 + t] + sred[9 + t];
    }
}

extern "C" void kernel_launch(void* const* d_in, const int* in_sizes, int n_in,
                              void* d_out, int out_size, void* d_ws, size_t ws_size,
                              hipStream_t stream) {
    const float* L   = (const float*)d_in[0];  // layer_input [N,1,3]
    const float* rbf = (const float*)d_in[1];  // rbf_inputs [N,N,32]
    const float* rij = (const float*)d_in[2];  // rij [N,N,3]
    const float* W1  = (const float*)d_in[3];
    const float* b1  = (const float*)d_in[4];
    const float* W2  = (const float*)d_in[5];
    const float* b2  = (const float*)d_in[6];
    float* out = (float*)d_out;

    const int N = in_sizes[0] / 3;  // 2048

    f1o1_kernel<<<N, BLOCK, 0, stream>>>(L, rbf, rij, W1, b1, W2, b2, out, N);
}